// Round 3
// baseline (8158.013 us; speedup 1.0000x reference)
//
#include <hip/hip_runtime.h>
#include <hip/hip_bf16.h>
#include <math.h>

#define S 2048
#define NH 4
#define FD 512
#define CHUNK 1024
#define BASE_LR_INV -6.9072552373f

// ---------------------------------------------------------------------------
// GEMM kernels: 64x64 tile, 256 threads (16x16), 4x4 microtile, k-major LDS.
// Batched via blockIdx.z with offsets: off = (z>>2)*offO + (z&3)*offI.
// M,N multiples of 64, K multiple of 16 (true for all shapes here).
// ---------------------------------------------------------------------------

// C = A @ B^T   A:(M,K) lda, B:(N,K) ldb, C:(M,N) ldc
__global__ __launch_bounds__(256) void gemm_abt(
    const float* __restrict__ A, int lda, long offAo, long offAi,
    const float* __restrict__ B, int ldb, long offBo, long offBi,
    float* __restrict__ C, int ldc, long offCo, long offCi, int K)
{
    int z = blockIdx.z;
    A += (long)(z >> 2) * offAo + (long)(z & 3) * offAi;
    B += (long)(z >> 2) * offBo + (long)(z & 3) * offBi;
    C += (long)(z >> 2) * offCo + (long)(z & 3) * offCi;
    __shared__ float As[16][68];
    __shared__ float Bs[16][68];
    int tid = threadIdx.x;
    int tx = tid & 15, ty = tid >> 4;
    int row0 = blockIdx.y * 64, col0 = blockIdx.x * 64;
    float acc[4][4] = {};
    for (int kk = 0; kk < K; kk += 16) {
        for (int i = tid; i < 1024; i += 256) {
            int r = i >> 4, c = i & 15;   // r: m/n index, c: k index
            As[c][r] = A[(long)(row0 + r) * lda + kk + c];
            Bs[c][r] = B[(long)(col0 + r) * ldb + kk + c];
        }
        __syncthreads();
#pragma unroll
        for (int k = 0; k < 16; ++k) {
            float4 ra = *reinterpret_cast<const float4*>(&As[k][ty << 2]);
            float4 rb = *reinterpret_cast<const float4*>(&Bs[k][tx << 2]);
            float fa[4] = {ra.x, ra.y, ra.z, ra.w};
            float fb[4] = {rb.x, rb.y, rb.z, rb.w};
#pragma unroll
            for (int a = 0; a < 4; ++a)
#pragma unroll
                for (int b = 0; b < 4; ++b) acc[a][b] += fa[a] * fb[b];
        }
        __syncthreads();
    }
#pragma unroll
    for (int a = 0; a < 4; ++a) {
        float4 o = make_float4(acc[a][0], acc[a][1], acc[a][2], acc[a][3]);
        *reinterpret_cast<float4*>(&C[(long)(row0 + ty * 4 + a) * ldc + col0 + tx * 4]) = o;
    }
}

// C = A @ B     A:(M,K) lda, B:(K,N) ldb, C:(M,N) ldc
__global__ __launch_bounds__(256) void gemm_ab(
    const float* __restrict__ A, int lda, long offAo, long offAi,
    const float* __restrict__ B, int ldb, long offBo, long offBi,
    float* __restrict__ C, int ldc, long offCo, long offCi, int K)
{
    int z = blockIdx.z;
    A += (long)(z >> 2) * offAo + (long)(z & 3) * offAi;
    B += (long)(z >> 2) * offBo + (long)(z & 3) * offBi;
    C += (long)(z >> 2) * offCo + (long)(z & 3) * offCi;
    __shared__ float As[16][68];
    __shared__ float Bs[16][68];
    int tid = threadIdx.x;
    int tx = tid & 15, ty = tid >> 4;
    int row0 = blockIdx.y * 64, col0 = blockIdx.x * 64;
    float acc[4][4] = {};
    for (int kk = 0; kk < K; kk += 16) {
        for (int i = tid; i < 1024; i += 256) {
            int r = i >> 4, c = i & 15;
            As[c][r] = A[(long)(row0 + r) * lda + kk + c];
        }
        for (int i = tid; i < 1024; i += 256) {
            int r = i >> 6, c = i & 63;  // r: k, c: n
            Bs[r][c] = B[(long)(kk + r) * ldb + col0 + c];
        }
        __syncthreads();
#pragma unroll
        for (int k = 0; k < 16; ++k) {
            float4 ra = *reinterpret_cast<const float4*>(&As[k][ty << 2]);
            float4 rb = *reinterpret_cast<const float4*>(&Bs[k][tx << 2]);
            float fa[4] = {ra.x, ra.y, ra.z, ra.w};
            float fb[4] = {rb.x, rb.y, rb.z, rb.w};
#pragma unroll
            for (int a = 0; a < 4; ++a)
#pragma unroll
                for (int b = 0; b < 4; ++b) acc[a][b] += fa[a] * fb[b];
        }
        __syncthreads();
    }
#pragma unroll
    for (int a = 0; a < 4; ++a) {
        float4 o = make_float4(acc[a][0], acc[a][1], acc[a][2], acc[a][3]);
        *reinterpret_cast<float4*>(&C[(long)(row0 + ty * 4 + a) * ldc + col0 + tx * 4]) = o;
    }
}

// C += A^T @ B  A:(K,M) lda, B:(K,N) ldb, C:(M,N) ldc
__global__ __launch_bounds__(256) void gemm_atb_acc(
    const float* __restrict__ A, int lda, long offAo, long offAi,
    const float* __restrict__ B, int ldb, long offBo, long offBi,
    float* __restrict__ C, int ldc, long offCo, long offCi, int K)
{
    int z = blockIdx.z;
    A += (long)(z >> 2) * offAo + (long)(z & 3) * offAi;
    B += (long)(z >> 2) * offBo + (long)(z & 3) * offBi;
    C += (long)(z >> 2) * offCo + (long)(z & 3) * offCi;
    __shared__ float As[16][68];
    __shared__ float Bs[16][68];
    int tid = threadIdx.x;
    int tx = tid & 15, ty = tid >> 4;
    int row0 = blockIdx.y * 64, col0 = blockIdx.x * 64;
    float acc[4][4] = {};
    for (int kk = 0; kk < K; kk += 16) {
        for (int i = tid; i < 1024; i += 256) {
            int r = i >> 6, c = i & 63;  // r: k, c: m/n
            As[r][c] = A[(long)(kk + r) * lda + row0 + c];
            Bs[r][c] = B[(long)(kk + r) * ldb + col0 + c];
        }
        __syncthreads();
#pragma unroll
        for (int k = 0; k < 16; ++k) {
            float4 ra = *reinterpret_cast<const float4*>(&As[k][ty << 2]);
            float4 rb = *reinterpret_cast<const float4*>(&Bs[k][tx << 2]);
            float fa[4] = {ra.x, ra.y, ra.z, ra.w};
            float fb[4] = {rb.x, rb.y, rb.z, rb.w};
#pragma unroll
            for (int a = 0; a < 4; ++a)
#pragma unroll
                for (int b = 0; b < 4; ++b) acc[a][b] += fa[a] * fb[b];
        }
        __syncthreads();
    }
#pragma unroll
    for (int a = 0; a < 4; ++a) {
        float* cp = &C[(long)(row0 + ty * 4 + a) * ldc + col0 + tx * 4];
        float4 o = *reinterpret_cast<float4*>(cp);
        o.x += acc[a][0]; o.y += acc[a][1]; o.z += acc[a][2]; o.w += acc[a][3];
        *reinterpret_cast<float4*>(cp) = o;
    }
}

// ---------------------------------------------------------------------------
// lr = softplus(hs @ lr_w^T + lr_b + BASE_LR_INV)  -> (4096, 12)
// ---------------------------------------------------------------------------
__global__ __launch_bounds__(256) void lr_kernel(
    const float* __restrict__ hs, const float* __restrict__ lr_w,
    const float* __restrict__ lr_b, float* __restrict__ lr)
{
    int row = blockIdx.x;
    __shared__ float hrow[2048];
    __shared__ float red[256];
    for (int i = threadIdx.x; i < 2048; i += 256) hrow[i] = hs[(long)row * 2048 + i];
    __syncthreads();
    for (int j = 0; j < 12; ++j) {
        float ss = 0.f;
        for (int i = threadIdx.x; i < 2048; i += 256) ss += hrow[i] * lr_w[(long)j * 2048 + i];
        red[threadIdx.x] = ss; __syncthreads();
        for (int s_ = 128; s_ > 0; s_ >>= 1) {
            if (threadIdx.x < s_) red[threadIdx.x] += red[threadIdx.x + s_];
            __syncthreads();
        }
        if (threadIdx.x == 0) {
            float x = red[0] + lr_b[j] + BASE_LR_INV;
            lr[(long)row * 12 + j] = (x > 20.f) ? x : log1pf(expf(x));
        }
        __syncthreads();
    }
}

// ---------------------------------------------------------------------------
// rmsnorm over d=2048 + RoPE per head (hd=128) -> packed (b,s,16,128)
// ---------------------------------------------------------------------------
__global__ __launch_bounds__(256) void rmsnorm_rope(
    const float* __restrict__ qkv, int colOff, const float* __restrict__ w,
    float* __restrict__ out)
{
    int row = blockIdx.x;            // b*s
    int si = row & (S - 1);
    const float* x = &qkv[(long)row * 6144 + colOff];
    __shared__ float xn[2048];
    __shared__ float red[256];
    float ss = 0.f;
    for (int i = threadIdx.x; i < 2048; i += 256) { float v = x[i]; ss += v * v; }
    red[threadIdx.x] = ss; __syncthreads();
    for (int s_ = 128; s_ > 0; s_ >>= 1) {
        if (threadIdx.x < s_) red[threadIdx.x] += red[threadIdx.x + s_];
        __syncthreads();
    }
    float scale = rsqrtf(red[0] / 2048.f + 1e-6f);
    for (int i = threadIdx.x; i < 2048; i += 256) xn[i] = x[i] * scale * w[i];
    __syncthreads();
    for (int i = threadIdx.x; i < 2048; i += 256) {
        int tt = i & 127;
        int t2 = tt & 63;
        float inv_freq = powf(500000.0f, -(float)t2 / 64.0f);
        float ang = (float)si * inv_freq;
        float sn, cs;
        sincosf(ang, &sn, &cs);
        float v;
        if (tt < 64) v = xn[i] * cs - xn[i + 64] * sn;
        else         v = xn[i] * cs + xn[i - 64] * sn;
        out[(long)row * 2048 + i] = v;
    }
}

// ---------------------------------------------------------------------------
// Sliding-window causal attention; one block (128 thr) per (b,h,q-row).
// ---------------------------------------------------------------------------
__global__ __launch_bounds__(128) void attn_kernel(
    const float* __restrict__ aq, const float* __restrict__ ak,
    const float* __restrict__ qkv, float* __restrict__ attn_out)
{
    int bid = blockIdx.x;
    int qi = bid & (S - 1);
    int h = (bid >> 11) & 15;
    int b_ = bid >> 15;
    __shared__ float qs[128];
    __shared__ float sc[1024];
    __shared__ float red[128];
    int t = threadIdx.x;
    const float scale = 0.088388347648318447f;  // 1/sqrt(128)
    qs[t] = aq[(long)(b_ * S + qi) * 2048 + h * 128 + t];
    __syncthreads();
    int jlo = qi - 1023; if (jlo < 0) jlo = 0;
    int nk = qi - jlo + 1;
    for (int jj = t; jj < nk; jj += 128) {
        const float* kr = &ak[(long)(b_ * S + jlo + jj) * 2048 + h * 128];
        float d = 0.f;
#pragma unroll 8
        for (int c = 0; c < 128; ++c) d += qs[c] * kr[c];
        sc[jj] = d * scale;
    }
    __syncthreads();
    float m = -INFINITY;
    for (int jj = t; jj < nk; jj += 128) m = fmaxf(m, sc[jj]);
    red[t] = m; __syncthreads();
    for (int s_ = 64; s_ > 0; s_ >>= 1) {
        if (t < s_) red[t] = fmaxf(red[t], red[t + s_]);
        __syncthreads();
    }
    m = red[0]; __syncthreads();
    float sum = 0.f;
    for (int jj = t; jj < nk; jj += 128) { float e = expf(sc[jj] - m); sc[jj] = e; sum += e; }
    red[t] = sum; __syncthreads();
    for (int s_ = 64; s_ > 0; s_ >>= 1) {
        if (t < s_) red[t] += red[t + s_];
        __syncthreads();
    }
    float inv = 1.0f / red[0];
    float o = 0.f;
    const float* vbase = &qkv[(long)(b_ * S + jlo) * 6144 + 4096 + h * 128 + t];
    for (int jj = 0; jj < nk; ++jj) o += sc[jj] * vbase[(long)jj * 6144];
    attn_out[(long)(b_ * S + qi) * 2048 + h * 128 + t] = o * inv;
}

// ---------------------------------------------------------------------------
// fq/fk/fv: silu (+affine for q/k) (+L2 norm over fd=512 for q/k)
// mode 0: q, 1: k, 2: v. Block (128 thr) per (row, nh).
// ---------------------------------------------------------------------------
__global__ __launch_bounds__(128) void fqkv_kernel(
    const float* __restrict__ qkv, const float* __restrict__ qk_scale,
    const float* __restrict__ qk_offset, float* __restrict__ out, int mode)
{
    int bid = blockIdx.x;
    int nh = bid & 3;
    int row = bid >> 2;
    const float* x = &qkv[(long)row * 6144 + mode * 2048 + nh * 512];
    __shared__ float red[128];
    float vals[4];
    float ss = 0.f;
#pragma unroll
    for (int ii = 0; ii < 4; ++ii) {
        int i = threadIdx.x + ii * 128;
        float v = x[i];
        float sg = 1.f / (1.f + expf(-v));
        float sv = v * sg;
        if (mode < 2) {
            int dcol = nh * 512 + i;
            sv = sv * qk_scale[dcol * 2 + mode] + qk_offset[dcol * 2 + mode];
        }
        vals[ii] = sv;
        ss += sv * sv;
    }
    float invn = 1.0f;
    if (mode < 2) {
        red[threadIdx.x] = ss; __syncthreads();
        for (int s_ = 64; s_ > 0; s_ >>= 1) {
            if (threadIdx.x < s_) red[threadIdx.x] += red[threadIdx.x + s_];
            __syncthreads();
        }
        invn = 1.0f / (sqrtf(red[0]) + 1e-12f);
    }
    float* o = &out[(long)row * 2048 + nh * 512];
#pragma unroll
    for (int ii = 0; ii < 4; ++ii) o[threadIdx.x + ii * 128] = vals[ii] * invn;
}

// ---------------------------------------------------------------------------
// fast-weight init: tile (4,512,512) x b=2 -> (8,512,512) for w0,w1,w2
// ---------------------------------------------------------------------------
__global__ void winit(const float* __restrict__ w0, const float* __restrict__ w1,
                      const float* __restrict__ w2, float* __restrict__ w0b,
                      float* __restrict__ w1b, float* __restrict__ w2b)
{
    long idx = (long)blockIdx.x * 256 + threadIdx.x;  // 8*512*512
    long src = ((idx >> 18) & 3) * 262144 + (idx & 262143);
    w0b[idx] = w0[src];
    w1b[idx] = w1[src];
    w2b[idx] = w2[src];
}

// ---------------------------------------------------------------------------
// scan elementwise 1: from gate(T1), hpre(T2), dh(T3) compute
//   T1 = dgate*l0, T2 = dhpre*l2, T3 = fv*l1, T4 = hid
// No __restrict__: T1..T3 alias the inputs (same-index read-before-write).
// ---------------------------------------------------------------------------
__global__ void scan_ew1(const float* gate, const float* hpre, const float* dhb,
                         const float* fv, const float* lr, int c0,
                         float* T1, float* T2, float* T3, float* T4)
{
    long idx = (long)blockIdx.x * 256 + threadIdx.x;  // 8*1024*512
    int f = idx & 511;
    long r = idx >> 9;
    int ci = (int)(r & 1023);
    int z = (int)(r >> 10);
    int b_ = z >> 2, h = z & 3;
    long srow = (long)b_ * S + (long)c0 * CHUNK + ci;
    float g = gate[idx], hp = hpre[idx], dh = dhb[idx];
    float sg = 1.f / (1.f + expf(-g));
    float silu_g = g * sg;
    float hid = silu_g * hp;
    float dgate = dh * hp * (sg * (1.f + g * (1.f - sg)));
    float dhpre = dh * silu_g;
    float l0 = lr[srow * 12 + h];
    float l1 = lr[srow * 12 + 4 + h];
    float l2 = lr[srow * 12 + 8 + h];
    float fvv = fv[srow * 2048 + h * 512 + f];
    T1[idx] = dgate * l0;
    T2[idx] = dhpre * l2;
    T3[idx] = fvv * l1;
    T4[idx] = hid;
}

// scan elementwise 2: T1 = silu(T1) * T2
__global__ void scan_ew2(float* T1, const float* T2)
{
    long idx = (long)blockIdx.x * 256 + threadIdx.x;
    float g = T1[idx];
    T1[idx] = g * (1.f / (1.f + expf(-g))) * T2[idx];
}

// ---------------------------------------------------------------------------
// ttt rmsnorm (fd=512, weight ttt_norm_w) added into attn_out in place
// ---------------------------------------------------------------------------
__global__ __launch_bounds__(128) void ttt_norm_add(
    const float* __restrict__ ttt, const float* __restrict__ w, float* attnX)
{
    int bid = blockIdx.x;
    int h = bid & 3;
    int row = bid >> 2;
    const float* x = &ttt[(long)row * 2048 + h * 512];
    __shared__ float red[128];
    float v[4];
    float ss = 0.f;
#pragma unroll
    for (int ii = 0; ii < 4; ++ii) {
        v[ii] = x[threadIdx.x + ii * 128];
        ss += v[ii] * v[ii];
    }
    red[threadIdx.x] = ss; __syncthreads();
    for (int s_ = 64; s_ > 0; s_ >>= 1) {
        if (threadIdx.x < s_) red[threadIdx.x] += red[threadIdx.x + s_];
        __syncthreads();
    }
    float sc = rsqrtf(red[0] / 512.f + 1e-6f);
    float* o = &attnX[(long)row * 2048 + h * 512];
#pragma unroll
    for (int ii = 0; ii < 4; ++ii) {
        int i = threadIdx.x + ii * 128;
        o[i] = o[i] + v[ii] * sc * w[i];
    }
}

// ---------------------------------------------------------------------------
extern "C" void kernel_launch(void* const* d_in, const int* in_sizes, int n_in,
                              void* d_out, int out_size, void* d_ws, size_t ws_size,
                              hipStream_t stream)
{
    const float* hs        = (const float*)d_in[0];
    const float* Wqkv      = (const float*)d_in[1];
    const float* Wo        = (const float*)d_in[2];
    const float* q_norm_w  = (const float*)d_in[3];
    const float* k_norm_w  = (const float*)d_in[4];
    const float* w0        = (const float*)d_in[5];
    const float* w1        = (const float*)d_in[6];
    const float* w2        = (const float*)d_in[7];
    const float* lr_w      = (const float*)d_in[8];
    const float* lr_b      = (const float*)d_in[9];
    const float* qk_scale  = (const float*)d_in[10];
    const float* qk_offset = (const float*)d_in[11];
    const float* ttt_w     = (const float*)d_in[12];
    float* out = (float*)d_out;
    float* ws = (float*)d_ws;

    // workspace layout (fp32 elements), total 65,060,864 floats = 248.2 MiB
    const long F_QKV = 0;          // 4096x6144 = 25,165,824. After fqkv this
                                   // region is dead and is reused as:
    const long F_TTT = 0;          //   ttt (b,s,NH,fd) 8,388,608
    const long F_T1  = 8388608;    //   T1..T4: 4x 4,194,304 = 16,777,216
    const long F_T2  = 12582912;
    const long F_T3  = 16777216;
    const long F_T4  = 20971520;   //   (exactly fills the qkv extent)
    const long F_AQ  = 25165824;   // aq, later fq   (8,388,608)
    const long F_AK  = 33554432;   // ak, later fk   (8,388,608)
    const long F_ATT = 41943040;   // attn_out / X   (8,388,608)
    const long F_FV  = 50331648;   // fv             (8,388,608)
    const long F_LR  = 58720256;   // lr             (49,152)
    const long F_W0  = 58769408;   // (8,512,512)
    const long F_W1  = 60866560;
    const long F_W2  = 62963712;   // end 65,060,864

    // 1. qkv = hs @ Wqkv^T
    gemm_abt<<<dim3(96, 64, 1), 256, 0, stream>>>(
        hs, 2048, 0, 0, Wqkv, 2048, 0, 0, ws + F_QKV, 6144, 0, 0, 2048);
    // 2. lr
    lr_kernel<<<4096, 256, 0, stream>>>(hs, lr_w, lr_b, ws + F_LR);
    // 3. rmsnorm + rope
    rmsnorm_rope<<<4096, 256, 0, stream>>>(ws + F_QKV, 0,    q_norm_w, ws + F_AQ);
    rmsnorm_rope<<<4096, 256, 0, stream>>>(ws + F_QKV, 2048, k_norm_w, ws + F_AK);
    // 4. attention
    attn_kernel<<<65536, 128, 0, stream>>>(ws + F_AQ, ws + F_AK, ws + F_QKV, ws + F_ATT);
    // 5. fq/fk/fv (reuse aq/ak buffers) — last readers of qkv
    fqkv_kernel<<<16384, 128, 0, stream>>>(ws + F_QKV, qk_scale, qk_offset, ws + F_AQ, 0);
    fqkv_kernel<<<16384, 128, 0, stream>>>(ws + F_QKV, qk_scale, qk_offset, ws + F_AK, 1);
    fqkv_kernel<<<16384, 128, 0, stream>>>(ws + F_QKV, qk_scale, qk_offset, ws + F_FV, 2);
    // 6. fast-weight init
    winit<<<8192, 256, 0, stream>>>(w0, w1, w2, ws + F_W0, ws + F_W1, ws + F_W2);

    // strides: chunk views of (b,s,NH,fd): row stride 2048; z = b*4+h
    const long sOb = 4194304, sOi = 512;      // (z>>2)*b-stride, (z&3)*head-stride
    const long wOb = 1048576, wOi = 262144;   // weights (8,512,512)
    const long tOb = 2097152, tOi = 524288;   // temps   (8,1024,512)

    for (int c0 = 0; c0 < 2; ++c0) {
        const float* fq = ws + F_AQ + (long)c0 * CHUNK * 2048;
        const float* fk = ws + F_AK + (long)c0 * CHUNK * 2048;
        const float* fv = ws + F_FV + (long)c0 * CHUNK * 2048;
        float* ttt = ws + F_TTT + (long)c0 * CHUNK * 2048;

        // gate = ki @ w0^T ; hpre = ki @ w2^T ; dh = vi @ w1
        gemm_abt<<<dim3(8, 16, 8), 256, 0, stream>>>(
            fk, 2048, sOb, sOi, ws + F_W0, 512, wOb, wOi, ws + F_T1, 512, tOb, tOi, 512);
        gemm_abt<<<dim3(8, 16, 8), 256, 0, stream>>>(
            fk, 2048, sOb, sOi, ws + F_W2, 512, wOb, wOi, ws + F_T2, 512, tOb, tOi, 512);
        gemm_ab<<<dim3(8, 16, 8), 256, 0, stream>>>(
            fv, 2048, sOb, sOi, ws + F_W1, 512, wOb, wOi, ws + F_T3, 512, tOb, tOi, 512);
        // elementwise: T1=dgate*l0, T2=dhpre*l2, T3=fv*l1, T4=hid
        scan_ew1<<<16384, 256, 0, stream>>>(ws + F_T1, ws + F_T2, ws + F_T3,
                                            ws + F_FV, ws + F_LR, c0,
                                            ws + F_T1, ws + F_T2, ws + F_T3, ws + F_T4);
        // weight updates (C += A^T B)
        gemm_atb_acc<<<dim3(8, 8, 8), 256, 0, stream>>>(
            ws + F_T1, 512, tOb, tOi, fk, 2048, sOb, sOi, ws + F_W0, 512, wOb, wOi, 1024);
        gemm_atb_acc<<<dim3(8, 8, 8), 256, 0, stream>>>(
            ws + F_T2, 512, tOb, tOi, fk, 2048, sOb, sOi, ws + F_W2, 512, wOb, wOi, 1024);
        gemm_atb_acc<<<dim3(8, 8, 8), 256, 0, stream>>>(
            ws + F_T3, 512, tOb, tOi, ws + F_T4, 512, tOb, tOi, ws + F_W1, 512, wOb, wOi, 1024);
        // query pass with updated weights
        gemm_abt<<<dim3(8, 16, 8), 256, 0, stream>>>(
            fq, 2048, sOb, sOi, ws + F_W0, 512, wOb, wOi, ws + F_T1, 512, tOb, tOi, 512);
        gemm_abt<<<dim3(8, 16, 8), 256, 0, stream>>>(
            fq, 2048, sOb, sOi, ws + F_W2, 512, wOb, wOi, ws + F_T2, 512, tOb, tOi, 512);
        scan_ew2<<<16384, 256, 0, stream>>>(ws + F_T1, ws + F_T2);
        // oi = hq @ w1^T -> ttt (strided into (b,s,NH,fd))
        gemm_abt<<<dim3(8, 16, 8), 256, 0, stream>>>(
            ws + F_T1, 512, tOb, tOi, ws + F_W1, 512, wOb, wOi, ttt, 2048, sOb, sOi, 512);
    }

    // 8. ttt rmsnorm + add into attn_out
    ttt_norm_add<<<16384, 128, 0, stream>>>(ws + F_TTT, ttt_w, ws + F_ATT);
    // 9. out = X @ Wo^T
    gemm_abt<<<dim3(32, 64, 1), 256, 0, stream>>>(
        ws + F_ATT, 2048, 0, 0, Wo, 2048, 0, 0, out, 2048, 0, 0, 2048);
}

// Round 4
// 4956.982 us; speedup vs baseline: 1.6458x; 1.6458x over previous
//
#include <hip/hip_runtime.h>
#include <hip/hip_bf16.h>
#include <math.h>

#define S 2048
#define NH 4
#define FD 512
#define CHUNK 1024
#define BASE_LR_INV -6.9072552373f

// ---------------------------------------------------------------------------
// GEMM kernels: 64x64 tile, 256 threads (16x16), 4x4 microtile, k-major LDS.
// Batched via blockIdx.z with offsets: off = (z>>2)*offO + (z&3)*offI.
// ---------------------------------------------------------------------------

// C = A @ B^T   A:(M,K) lda, B:(N,K) ldb, C:(M,N) ldc
__global__ __launch_bounds__(256) void gemm_abt(
    const float* __restrict__ A, int lda, long offAo, long offAi,
    const float* __restrict__ B, int ldb, long offBo, long offBi,
    float* __restrict__ C, int ldc, long offCo, long offCi, int K)
{
    int z = blockIdx.z;
    A += (long)(z >> 2) * offAo + (long)(z & 3) * offAi;
    B += (long)(z >> 2) * offBo + (long)(z & 3) * offBi;
    C += (long)(z >> 2) * offCo + (long)(z & 3) * offCi;
    __shared__ float As[16][68];
    __shared__ float Bs[16][68];
    int tid = threadIdx.x;
    int tx = tid & 15, ty = tid >> 4;
    int row0 = blockIdx.y * 64, col0 = blockIdx.x * 64;
    float acc[4][4] = {};
    for (int kk = 0; kk < K; kk += 16) {
        for (int i = tid; i < 1024; i += 256) {
            int r = i >> 4, c = i & 15;   // r: m/n index, c: k index
            As[c][r] = A[(long)(row0 + r) * lda + kk + c];
            Bs[c][r] = B[(long)(col0 + r) * ldb + kk + c];
        }
        __syncthreads();
#pragma unroll
        for (int k = 0; k < 16; ++k) {
            float4 ra = *reinterpret_cast<const float4*>(&As[k][ty << 2]);
            float4 rb = *reinterpret_cast<const float4*>(&Bs[k][tx << 2]);
            float fa[4] = {ra.x, ra.y, ra.z, ra.w};
            float fb[4] = {rb.x, rb.y, rb.z, rb.w};
#pragma unroll
            for (int a = 0; a < 4; ++a)
#pragma unroll
                for (int b = 0; b < 4; ++b) acc[a][b] += fa[a] * fb[b];
        }
        __syncthreads();
    }
#pragma unroll
    for (int a = 0; a < 4; ++a) {
        float4 o = make_float4(acc[a][0], acc[a][1], acc[a][2], acc[a][3]);
        *reinterpret_cast<float4*>(&C[(long)(row0 + ty * 4 + a) * ldc + col0 + tx * 4]) = o;
    }
}

// C = A @ B     A:(M,K) lda, B:(K,N) ldb, C:(M,N) ldc
__global__ __launch_bounds__(256) void gemm_ab(
    const float* __restrict__ A, int lda, long offAo, long offAi,
    const float* __restrict__ B, int ldb, long offBo, long offBi,
    float* __restrict__ C, int ldc, long offCo, long offCi, int K)
{
    int z = blockIdx.z;
    A += (long)(z >> 2) * offAo + (long)(z & 3) * offAi;
    B += (long)(z >> 2) * offBo + (long)(z & 3) * offBi;
    C += (long)(z >> 2) * offCo + (long)(z & 3) * offCi;
    __shared__ float As[16][68];
    __shared__ float Bs[16][68];
    int tid = threadIdx.x;
    int tx = tid & 15, ty = tid >> 4;
    int row0 = blockIdx.y * 64, col0 = blockIdx.x * 64;
    float acc[4][4] = {};
    for (int kk = 0; kk < K; kk += 16) {
        for (int i = tid; i < 1024; i += 256) {
            int r = i >> 4, c = i & 15;
            As[c][r] = A[(long)(row0 + r) * lda + kk + c];
        }
        for (int i = tid; i < 1024; i += 256) {
            int r = i >> 6, c = i & 63;  // r: k, c: n
            Bs[r][c] = B[(long)(kk + r) * ldb + col0 + c];
        }
        __syncthreads();
#pragma unroll
        for (int k = 0; k < 16; ++k) {
            float4 ra = *reinterpret_cast<const float4*>(&As[k][ty << 2]);
            float4 rb = *reinterpret_cast<const float4*>(&Bs[k][tx << 2]);
            float fa[4] = {ra.x, ra.y, ra.z, ra.w};
            float fb[4] = {rb.x, rb.y, rb.z, rb.w};
#pragma unroll
            for (int a = 0; a < 4; ++a)
#pragma unroll
                for (int b = 0; b < 4; ++b) acc[a][b] += fa[a] * fb[b];
        }
        __syncthreads();
    }
#pragma unroll
    for (int a = 0; a < 4; ++a) {
        float4 o = make_float4(acc[a][0], acc[a][1], acc[a][2], acc[a][3]);
        *reinterpret_cast<float4*>(&C[(long)(row0 + ty * 4 + a) * ldc + col0 + tx * 4]) = o;
    }
}

// C += A^T @ B  A:(K,M) lda, B:(K,N) ldb, C:(M,N) ldc
__global__ __launch_bounds__(256) void gemm_atb_acc(
    const float* __restrict__ A, int lda, long offAo, long offAi,
    const float* __restrict__ B, int ldb, long offBo, long offBi,
    float* __restrict__ C, int ldc, long offCo, long offCi, int K)
{
    int z = blockIdx.z;
    A += (long)(z >> 2) * offAo + (long)(z & 3) * offAi;
    B += (long)(z >> 2) * offBo + (long)(z & 3) * offBi;
    C += (long)(z >> 2) * offCo + (long)(z & 3) * offCi;
    __shared__ float As[16][68];
    __shared__ float Bs[16][68];
    int tid = threadIdx.x;
    int tx = tid & 15, ty = tid >> 4;
    int row0 = blockIdx.y * 64, col0 = blockIdx.x * 64;
    float acc[4][4] = {};
    for (int kk = 0; kk < K; kk += 16) {
        for (int i = tid; i < 1024; i += 256) {
            int r = i >> 6, c = i & 63;  // r: k, c: m/n
            As[r][c] = A[(long)(kk + r) * lda + row0 + c];
            Bs[r][c] = B[(long)(kk + r) * ldb + col0 + c];
        }
        __syncthreads();
#pragma unroll
        for (int k = 0; k < 16; ++k) {
            float4 ra = *reinterpret_cast<const float4*>(&As[k][ty << 2]);
            float4 rb = *reinterpret_cast<const float4*>(&Bs[k][tx << 2]);
            float fa[4] = {ra.x, ra.y, ra.z, ra.w};
            float fb[4] = {rb.x, rb.y, rb.z, rb.w};
#pragma unroll
            for (int a = 0; a < 4; ++a)
#pragma unroll
                for (int b = 0; b < 4; ++b) acc[a][b] += fa[a] * fb[b];
        }
        __syncthreads();
    }
#pragma unroll
    for (int a = 0; a < 4; ++a) {
        float* cp = &C[(long)(row0 + ty * 4 + a) * ldc + col0 + tx * 4];
        float4 o = *reinterpret_cast<float4*>(cp);
        o.x += acc[a][0]; o.y += acc[a][1]; o.z += acc[a][2]; o.w += acc[a][3];
        *reinterpret_cast<float4*>(cp) = o;
    }
}

// ---------------------------------------------------------------------------
// lr = softplus(hs @ lr_w^T + lr_b + BASE_LR_INV)  -> (4096, 12)
// ---------------------------------------------------------------------------
__global__ __launch_bounds__(256) void lr_kernel(
    const float* __restrict__ hs, const float* __restrict__ lr_w,
    const float* __restrict__ lr_b, float* __restrict__ lr)
{
    int row = blockIdx.x;
    __shared__ float hrow[2048];
    __shared__ float red[256];
    for (int i = threadIdx.x; i < 2048; i += 256) hrow[i] = hs[(long)row * 2048 + i];
    __syncthreads();
    for (int j = 0; j < 12; ++j) {
        float ss = 0.f;
        for (int i = threadIdx.x; i < 2048; i += 256) ss += hrow[i] * lr_w[(long)j * 2048 + i];
        red[threadIdx.x] = ss; __syncthreads();
        for (int s_ = 128; s_ > 0; s_ >>= 1) {
            if (threadIdx.x < s_) red[threadIdx.x] += red[threadIdx.x + s_];
            __syncthreads();
        }
        if (threadIdx.x == 0) {
            float x = red[0] + lr_b[j] + BASE_LR_INV;
            lr[(long)row * 12 + j] = (x > 20.f) ? x : log1pf(expf(x));
        }
        __syncthreads();
    }
}

// ---------------------------------------------------------------------------
// rmsnorm over d=2048 + RoPE per head (hd=128) -> packed (b,s,16,128)
// ---------------------------------------------------------------------------
__global__ __launch_bounds__(256) void rmsnorm_rope(
    const float* __restrict__ qkv, int colOff, const float* __restrict__ w,
    float* __restrict__ out)
{
    int row = blockIdx.x;            // b*s
    int si = row & (S - 1);
    const float* x = &qkv[(long)row * 6144 + colOff];
    __shared__ float xn[2048];
    __shared__ float red[256];
    float ss = 0.f;
    for (int i = threadIdx.x; i < 2048; i += 256) { float v = x[i]; ss += v * v; }
    red[threadIdx.x] = ss; __syncthreads();
    for (int s_ = 128; s_ > 0; s_ >>= 1) {
        if (threadIdx.x < s_) red[threadIdx.x] += red[threadIdx.x + s_];
        __syncthreads();
    }
    float scale = rsqrtf(red[0] / 2048.f + 1e-6f);
    for (int i = threadIdx.x; i < 2048; i += 256) xn[i] = x[i] * scale * w[i];
    __syncthreads();
    for (int i = threadIdx.x; i < 2048; i += 256) {
        int tt = i & 127;
        int t2 = tt & 63;
        float inv_freq = powf(500000.0f, -(float)t2 / 64.0f);
        float ang = (float)si * inv_freq;
        float sn, cs;
        sincosf(ang, &sn, &cs);
        float v;
        if (tt < 64) v = xn[i] * cs - xn[i + 64] * sn;
        else         v = xn[i] * cs + xn[i - 64] * sn;
        out[(long)row * 2048 + i] = v;
    }
}

// ---------------------------------------------------------------------------
// Flash-style sliding-window causal attention.
// Block 256 thr (16x16) per (64-row q-tile, head, batch). K/V tiles of 64.
// Scores: 4x4 microtile GEMM; online softmax; PV: 4 rows x 8 cols per thread.
// ---------------------------------------------------------------------------
__global__ __launch_bounds__(256) void attn_tiled(
    const float* __restrict__ aq, const float* __restrict__ ak,
    const float* __restrict__ qkv, float* __restrict__ attn_out)
{
    const int qt = blockIdx.x;          // 0..31
    const int h  = blockIdx.y;          // 0..15
    const int b_ = blockIdx.z;          // 0..1
    const int q0 = qt * 64;
    const int tid = threadIdx.x;
    const int tx = tid & 15, ty = tid >> 4;
    const float scale = 0.088388347648318447f;   // 1/sqrt(128)

    __shared__ float As[16][68];     // Q chunk  [c][qrow]
    __shared__ float Bs[16][68];     // K chunk  [c][krow]
    __shared__ float Ps[64][65];     // probabilities [qrow][kcol] (65: bank-stride break)
    __shared__ float Vs[16][132];    // V chunk  [krow][c]
    __shared__ float rowred[64][17]; // per-row reduction partials
    __shared__ float tmax[64], tsum[64];

    float O[4][8] = {};
    float m_i[4] = {-3.4e38f, -3.4e38f, -3.4e38f, -3.4e38f};
    float l_i[4] = {};

    const long qbase = (long)(b_ * S + q0) * 2048 + h * 128;

    const int st = (qt >= 16) ? (qt - 16) : 0;
    for (int kt = st; kt <= qt; ++kt) {
        const int j0 = kt * 64;
        const long kbase = (long)(b_ * S + j0) * 2048 + h * 128;

        // ---- scores S = Q @ K^T (64x64, reduce c=128) ----
        float acc[4][4] = {};
        for (int cc = 0; cc < 128; cc += 16) {
            for (int i = tid; i < 1024; i += 256) {
                int r = i >> 4, c = i & 15;
                As[c][r] = aq[qbase + (long)r * 2048 + cc + c];
                Bs[c][r] = ak[kbase + (long)r * 2048 + cc + c];
            }
            __syncthreads();
#pragma unroll
            for (int k = 0; k < 16; ++k) {
                float4 ra = *reinterpret_cast<const float4*>(&As[k][ty << 2]);
                float4 rb = *reinterpret_cast<const float4*>(&Bs[k][tx << 2]);
                float fa[4] = {ra.x, ra.y, ra.z, ra.w};
                float fb[4] = {rb.x, rb.y, rb.z, rb.w};
#pragma unroll
                for (int a = 0; a < 4; ++a)
#pragma unroll
                    for (int b = 0; b < 4; ++b) acc[a][b] += fa[a] * fb[b];
            }
            __syncthreads();
        }

        // ---- mask + tile row-max ----
        float s[4][4];
#pragma unroll
        for (int a = 0; a < 4; ++a) {
            int i_abs = q0 + ty * 4 + a;
            float rm = -3.4e38f;
#pragma unroll
            for (int b = 0; b < 4; ++b) {
                int j_abs = j0 + tx * 4 + b;
                bool valid = (j_abs <= i_abs) && (i_abs - j_abs < 1024);
                s[a][b] = valid ? acc[a][b] * scale : -3.4e38f;
                rm = fmaxf(rm, s[a][b]);
            }
            rowred[ty * 4 + a][tx] = rm;
        }
        __syncthreads();
        if (tid < 64) {
            float rm = -3.4e38f;
#pragma unroll
            for (int j = 0; j < 16; ++j) rm = fmaxf(rm, rowred[tid][j]);
            tmax[tid] = rm;
        }
        __syncthreads();

        // ---- online-softmax update; write P ----
        float alpha[4];
#pragma unroll
        for (int a = 0; a < 4; ++a) {
            int r = ty * 4 + a;
            float m_new = fmaxf(m_i[a], tmax[r]);
            alpha[a] = expf(m_i[a] - m_new);   // m_i==m_new==-3.4e38 -> exp(0)=1, O==0
            m_i[a] = m_new;
            float psum = 0.f;
#pragma unroll
            for (int b = 0; b < 4; ++b) {
                float p = (s[a][b] > -1e30f) ? expf(s[a][b] - m_new) : 0.f;
                Ps[r][tx * 4 + b] = p;
                psum += p;
            }
            rowred[r][tx] = psum;
#pragma unroll
            for (int c = 0; c < 8; ++c) O[a][c] *= alpha[a];
        }
        __syncthreads();
        if (tid < 64) {
            float rs = 0.f;
#pragma unroll
            for (int j = 0; j < 16; ++j) rs += rowred[tid][j];
            tsum[tid] = rs;
        }
        __syncthreads();
#pragma unroll
        for (int a = 0; a < 4; ++a)
            l_i[a] = l_i[a] * alpha[a] + tsum[ty * 4 + a];

        // ---- O += P @ V ----
        const long vbase = (long)(b_ * S + j0) * 6144 + 4096 + h * 128;
        for (int kc = 0; kc < 4; ++kc) {
            __syncthreads();  // previous Vs consumers done
            for (int i = tid; i < 512; i += 256) {   // 512 float4 = 16x128
                int kr = i >> 5, c4 = i & 31;
                *reinterpret_cast<float4*>(&Vs[kr][c4 * 4]) =
                    *reinterpret_cast<const float4*>(&qkv[vbase + (long)(kc * 16 + kr) * 6144 + c4 * 4]);
            }
            __syncthreads();
#pragma unroll
            for (int kk = 0; kk < 16; ++kk) {
                float fa[4];
#pragma unroll
                for (int a = 0; a < 4; ++a) fa[a] = Ps[ty * 4 + a][kc * 16 + kk];
                float4 v0 = *reinterpret_cast<const float4*>(&Vs[kk][tx * 8]);
                float4 v1 = *reinterpret_cast<const float4*>(&Vs[kk][tx * 8 + 4]);
                float fb[8] = {v0.x, v0.y, v0.z, v0.w, v1.x, v1.y, v1.z, v1.w};
#pragma unroll
                for (int a = 0; a < 4; ++a)
#pragma unroll
                    for (int c = 0; c < 8; ++c) O[a][c] += fa[a] * fb[c];
            }
        }
        __syncthreads();  // Ps/Vs free for next tile
    }

    // ---- normalize + store ----
#pragma unroll
    for (int a = 0; a < 4; ++a) {
        float inv = 1.0f / l_i[a];
        float4 o0 = make_float4(O[a][0] * inv, O[a][1] * inv, O[a][2] * inv, O[a][3] * inv);
        float4 o1 = make_float4(O[a][4] * inv, O[a][5] * inv, O[a][6] * inv, O[a][7] * inv);
        float* dst = &attn_out[qbase + (long)(ty * 4 + a) * 2048 + tx * 8];
        *reinterpret_cast<float4*>(dst) = o0;
        *reinterpret_cast<float4*>(dst + 4) = o1;
    }
}

// ---------------------------------------------------------------------------
// fq/fk/fv: silu (+affine for q/k) (+L2 norm over fd=512 for q/k)
// ---------------------------------------------------------------------------
__global__ __launch_bounds__(128) void fqkv_kernel(
    const float* __restrict__ qkv, const float* __restrict__ qk_scale,
    const float* __restrict__ qk_offset, float* __restrict__ out, int mode)
{
    int bid = blockIdx.x;
    int nh = bid & 3;
    int row = bid >> 2;
    const float* x = &qkv[(long)row * 6144 + mode * 2048 + nh * 512];
    __shared__ float red[128];
    float vals[4];
    float ss = 0.f;
#pragma unroll
    for (int ii = 0; ii < 4; ++ii) {
        int i = threadIdx.x + ii * 128;
        float v = x[i];
        float sg = 1.f / (1.f + expf(-v));
        float sv = v * sg;
        if (mode < 2) {
            int dcol = nh * 512 + i;
            sv = sv * qk_scale[dcol * 2 + mode] + qk_offset[dcol * 2 + mode];
        }
        vals[ii] = sv;
        ss += sv * sv;
    }
    float invn = 1.0f;
    if (mode < 2) {
        red[threadIdx.x] = ss; __syncthreads();
        for (int s_ = 64; s_ > 0; s_ >>= 1) {
            if (threadIdx.x < s_) red[threadIdx.x] += red[threadIdx.x + s_];
            __syncthreads();
        }
        invn = 1.0f / (sqrtf(red[0]) + 1e-12f);
    }
    float* o = &out[(long)row * 2048 + nh * 512];
#pragma unroll
    for (int ii = 0; ii < 4; ++ii) o[threadIdx.x + ii * 128] = vals[ii] * invn;
}

// ---------------------------------------------------------------------------
// fast-weight init: tile (4,512,512) x b=2 -> (8,512,512) for w0,w1,w2
// ---------------------------------------------------------------------------
__global__ void winit(const float* __restrict__ w0, const float* __restrict__ w1,
                      const float* __restrict__ w2, float* __restrict__ w0b,
                      float* __restrict__ w1b, float* __restrict__ w2b)
{
    long idx = (long)blockIdx.x * 256 + threadIdx.x;  // 8*512*512
    long src = ((idx >> 18) & 3) * 262144 + (idx & 262143);
    w0b[idx] = w0[src];
    w1b[idx] = w1[src];
    w2b[idx] = w2[src];
}

// ---------------------------------------------------------------------------
// scan elementwise 1: from gate(T1), hpre(T2), dh(T3) compute
//   T1 = dgate*l0, T2 = dhpre*l2, T3 = fv*l1, T4 = hid
// No __restrict__: T1..T3 alias the inputs (same-index read-before-write).
// ---------------------------------------------------------------------------
__global__ void scan_ew1(const float* gate, const float* hpre, const float* dhb,
                         const float* fv, const float* lr, int c0,
                         float* T1, float* T2, float* T3, float* T4)
{
    long idx = (long)blockIdx.x * 256 + threadIdx.x;  // 8*1024*512
    int f = idx & 511;
    long r = idx >> 9;
    int ci = (int)(r & 1023);
    int z = (int)(r >> 10);
    int b_ = z >> 2, h = z & 3;
    long srow = (long)b_ * S + (long)c0 * CHUNK + ci;
    float g = gate[idx], hp = hpre[idx], dh = dhb[idx];
    float sg = 1.f / (1.f + expf(-g));
    float silu_g = g * sg;
    float hid = silu_g * hp;
    float dgate = dh * hp * (sg * (1.f + g * (1.f - sg)));
    float dhpre = dh * silu_g;
    float l0 = lr[srow * 12 + h];
    float l1 = lr[srow * 12 + 4 + h];
    float l2 = lr[srow * 12 + 8 + h];
    float fvv = fv[srow * 2048 + h * 512 + f];
    T1[idx] = dgate * l0;
    T2[idx] = dhpre * l2;
    T3[idx] = fvv * l1;
    T4[idx] = hid;
}

// scan elementwise 2: T1 = silu(T1) * T2
__global__ void scan_ew2(float* T1, const float* T2)
{
    long idx = (long)blockIdx.x * 256 + threadIdx.x;
    float g = T1[idx];
    T1[idx] = g * (1.f / (1.f + expf(-g))) * T2[idx];
}

// ---------------------------------------------------------------------------
// ttt rmsnorm (fd=512, weight ttt_norm_w) added into attn_out in place
// ---------------------------------------------------------------------------
__global__ __launch_bounds__(128) void ttt_norm_add(
    const float* __restrict__ ttt, const float* __restrict__ w, float* attnX)
{
    int bid = blockIdx.x;
    int h = bid & 3;
    int row = bid >> 2;
    const float* x = &ttt[(long)row * 2048 + h * 512];
    __shared__ float red[128];
    float v[4];
    float ss = 0.f;
#pragma unroll
    for (int ii = 0; ii < 4; ++ii) {
        v[ii] = x[threadIdx.x + ii * 128];
        ss += v[ii] * v[ii];
    }
    red[threadIdx.x] = ss; __syncthreads();
    for (int s_ = 64; s_ > 0; s_ >>= 1) {
        if (threadIdx.x < s_) red[threadIdx.x] += red[threadIdx.x + s_];
        __syncthreads();
    }
    float sc = rsqrtf(red[0] / 512.f + 1e-6f);
    float* o = &attnX[(long)row * 2048 + h * 512];
#pragma unroll
    for (int ii = 0; ii < 4; ++ii) {
        int i = threadIdx.x + ii * 128;
        o[i] = o[i] + v[ii] * sc * w[i];
    }
}

// ---------------------------------------------------------------------------
extern "C" void kernel_launch(void* const* d_in, const int* in_sizes, int n_in,
                              void* d_out, int out_size, void* d_ws, size_t ws_size,
                              hipStream_t stream)
{
    const float* hs        = (const float*)d_in[0];
    const float* Wqkv      = (const float*)d_in[1];
    const float* Wo        = (const float*)d_in[2];
    const float* q_norm_w  = (const float*)d_in[3];
    const float* k_norm_w  = (const float*)d_in[4];
    const float* w0        = (const float*)d_in[5];
    const float* w1        = (const float*)d_in[6];
    const float* w2        = (const float*)d_in[7];
    const float* lr_w      = (const float*)d_in[8];
    const float* lr_b      = (const float*)d_in[9];
    const float* qk_scale  = (const float*)d_in[10];
    const float* qk_offset = (const float*)d_in[11];
    const float* ttt_w     = (const float*)d_in[12];
    float* out = (float*)d_out;
    float* ws = (float*)d_ws;

    // workspace layout (fp32 elements), total 65,060,864 floats = 248.2 MiB
    const long F_QKV = 0;          // 4096x6144 = 25,165,824; reused later as:
    const long F_TTT = 0;          //   ttt (b,s,NH,fd) 8,388,608
    const long F_T1  = 8388608;    //   T1..T4: 4x 4,194,304
    const long F_T2  = 12582912;
    const long F_T3  = 16777216;
    const long F_T4  = 20971520;
    const long F_AQ  = 25165824;   // aq, later fq   (8,388,608)
    const long F_AK  = 33554432;   // ak, later fk   (8,388,608)
    const long F_ATT = 41943040;   // attn_out / X   (8,388,608)
    const long F_FV  = 50331648;   // fv             (8,388,608)
    const long F_LR  = 58720256;   // lr             (49,152)
    const long F_W0  = 58769408;   // (8,512,512)
    const long F_W1  = 60866560;
    const long F_W2  = 62963712;   // end 65,060,864

    // 1. qkv = hs @ Wqkv^T
    gemm_abt<<<dim3(96, 64, 1), 256, 0, stream>>>(
        hs, 2048, 0, 0, Wqkv, 2048, 0, 0, ws + F_QKV, 6144, 0, 0, 2048);
    // 2. lr
    lr_kernel<<<4096, 256, 0, stream>>>(hs, lr_w, lr_b, ws + F_LR);
    // 3. rmsnorm + rope
    rmsnorm_rope<<<4096, 256, 0, stream>>>(ws + F_QKV, 0,    q_norm_w, ws + F_AQ);
    rmsnorm_rope<<<4096, 256, 0, stream>>>(ws + F_QKV, 2048, k_norm_w, ws + F_AK);
    // 4. attention (flash-style tiled)
    attn_tiled<<<dim3(32, 16, 2), 256, 0, stream>>>(
        ws + F_AQ, ws + F_AK, ws + F_QKV, ws + F_ATT);
    // 5. fq/fk/fv (reuse aq/ak buffers) — last readers of qkv
    fqkv_kernel<<<16384, 128, 0, stream>>>(ws + F_QKV, qk_scale, qk_offset, ws + F_AQ, 0);
    fqkv_kernel<<<16384, 128, 0, stream>>>(ws + F_QKV, qk_scale, qk_offset, ws + F_AK, 1);
    fqkv_kernel<<<16384, 128, 0, stream>>>(ws + F_QKV, qk_scale, qk_offset, ws + F_FV, 2);
    // 6. fast-weight init
    winit<<<8192, 256, 0, stream>>>(w0, w1, w2, ws + F_W0, ws + F_W1, ws + F_W2);

    // strides: chunk views of (b,s,NH,fd): row stride 2048; z = b*4+h
    const long sOb = 4194304, sOi = 512;      // (z>>2)*b-stride, (z&3)*head-stride
    const long wOb = 1048576, wOi = 262144;   // weights (8,512,512)
    const long tOb = 2097152, tOi = 524288;   // temps   (8,1024,512)

    for (int c0 = 0; c0 < 2; ++c0) {
        const float* fq = ws + F_AQ + (long)c0 * CHUNK * 2048;
        const float* fk = ws + F_AK + (long)c0 * CHUNK * 2048;
        const float* fv = ws + F_FV + (long)c0 * CHUNK * 2048;
        float* ttt = ws + F_TTT + (long)c0 * CHUNK * 2048;

        // gate = ki @ w0^T ; hpre = ki @ w2^T ; dh = vi @ w1
        gemm_abt<<<dim3(8, 16, 8), 256, 0, stream>>>(
            fk, 2048, sOb, sOi, ws + F_W0, 512, wOb, wOi, ws + F_T1, 512, tOb, tOi, 512);
        gemm_abt<<<dim3(8, 16, 8), 256, 0, stream>>>(
            fk, 2048, sOb, sOi, ws + F_W2, 512, wOb, wOi, ws + F_T2, 512, tOb, tOi, 512);
        gemm_ab<<<dim3(8, 16, 8), 256, 0, stream>>>(
            fv, 2048, sOb, sOi, ws + F_W1, 512, wOb, wOi, ws + F_T3, 512, tOb, tOi, 512);
        // elementwise: T1=dgate*l0, T2=dhpre*l2, T3=fv*l1, T4=hid
        scan_ew1<<<16384, 256, 0, stream>>>(ws + F_T1, ws + F_T2, ws + F_T3,
                                            ws + F_FV, ws + F_LR, c0,
                                            ws + F_T1, ws + F_T2, ws + F_T3, ws + F_T4);
        // weight updates (C += A^T B)
        gemm_atb_acc<<<dim3(8, 8, 8), 256, 0, stream>>>(
            ws + F_T1, 512, tOb, tOi, fk, 2048, sOb, sOi, ws + F_W0, 512, wOb, wOi, 1024);
        gemm_atb_acc<<<dim3(8, 8, 8), 256, 0, stream>>>(
            ws + F_T2, 512, tOb, tOi, fk, 2048, sOb, sOi, ws + F_W2, 512, wOb, wOi, 1024);
        gemm_atb_acc<<<dim3(8, 8, 8), 256, 0, stream>>>(
            ws + F_T3, 512, tOb, tOi, ws + F_T4, 512, tOb, tOi, ws + F_W1, 512, wOb, wOi, 1024);
        // query pass with updated weights
        gemm_abt<<<dim3(8, 16, 8), 256, 0, stream>>>(
            fq, 2048, sOb, sOi, ws + F_W0, 512, wOb, wOi, ws + F_T1, 512, tOb, tOi, 512);
        gemm_abt<<<dim3(8, 16, 8), 256, 0, stream>>>(
            fq, 2048, sOb, sOi, ws + F_W2, 512, wOb, wOi, ws + F_T2, 512, tOb, tOi, 512);
        scan_ew2<<<16384, 256, 0, stream>>>(ws + F_T1, ws + F_T2);
        // oi = hq @ w1^T -> ttt (strided into (b,s,NH,fd))
        gemm_abt<<<dim3(8, 16, 8), 256, 0, stream>>>(
            ws + F_T1, 512, tOb, tOi, ws + F_W1, 512, wOb, wOi, ttt, 2048, sOb, sOi, 512);
    }

    // 8. ttt rmsnorm + add into attn_out
    ttt_norm_add<<<16384, 128, 0, stream>>>(ws + F_TTT, ttt_w, ws + F_ATT);
    // 9. out = X @ Wo^T
    gemm_abt<<<dim3(32, 64, 1), 256, 0, stream>>>(
        ws + F_ATT, 2048, 0, 0, Wo, 2048, 0, 0, out, 2048, 0, 0, 2048);
}

// Round 5
// 1996.667 us; speedup vs baseline: 4.0858x; 2.4826x over previous
//
#include <hip/hip_runtime.h>
#include <hip/hip_bf16.h>
#include <math.h>

#define S 2048
#define NH 4
#define FD 512
#define CHUNK 1024
#define BASE_LR_INV -6.9072552373f

typedef unsigned short u16;
typedef unsigned int u32;
typedef short bhalf8 __attribute__((ext_vector_type(8)));   // 8 bf16 = 4 VGPRs
typedef float floatx4 __attribute__((ext_vector_type(4)));

__device__ __forceinline__ u16 f2bf(float f) {               // RNE fp32->bf16
    u32 x = __float_as_uint(f);
    return (u16)((x + 0x7FFFu + ((x >> 16) & 1u)) >> 16);
}
__device__ __forceinline__ float bf2f(u16 u) {
    return __uint_as_float(((u32)u) << 16);
}
__device__ __forceinline__ float ldval(const float* p) { return *p; }
__device__ __forceinline__ float ldval(const u16* p) { return bf2f(*p); }

// ---------------------------------------------------------------------------
// bf16 MFMA GEMM:  C(fp32) = A @ B^T, A:(M,K) bf16 lda, B:(N,K) bf16 ldb.
// 128x128 block tile, 256 thr = 4 waves (2x2 of 64x64), BK=32,
// v_mfma_f32_16x16x32_bf16. acc_flag: C += result.
// Batched: ptr += (z>>2)*offO + (z&3)*offI.
// M,N mult of 128; K mult of 32.
// ---------------------------------------------------------------------------
__global__ __launch_bounds__(256) void gemm_mfma(
    const u16* __restrict__ A, int lda, long offAo, long offAi,
    const u16* __restrict__ B, int ldb, long offBo, long offBi,
    float* __restrict__ C, int ldc, long offCo, long offCi, int K, int acc_flag)
{
    int z = blockIdx.z;
    A += (long)(z >> 2) * offAo + (long)(z & 3) * offAi;
    B += (long)(z >> 2) * offBo + (long)(z & 3) * offBi;
    C += (long)(z >> 2) * offCo + (long)(z & 3) * offCi;
    __shared__ u16 As[128][40];   // +8 pad: rows 80 B apart (16B-aligned)
    __shared__ u16 Bs[128][40];
    const int tid = threadIdx.x;
    const int wid = tid >> 6, lane = tid & 63;
    const int quad = lane >> 4, l15 = lane & 15;
    const int m0w = (wid >> 1) * 64, n0w = (wid & 1) * 64;
    const int row0 = blockIdx.y * 128, col0 = blockIdx.x * 128;
    const int srow = tid >> 1, scol = (tid & 1) * 16;   // staging map: 16 bf16/thread

    floatx4 acc[4][4];
#pragma unroll
    for (int a = 0; a < 4; ++a)
#pragma unroll
        for (int b = 0; b < 4; ++b) acc[a][b] = {0.f, 0.f, 0.f, 0.f};

    for (int kk = 0; kk < K; kk += 32) {
        const u16* ga = &A[(long)(row0 + srow) * lda + kk + scol];
        const u16* gb = &B[(long)(col0 + srow) * ldb + kk + scol];
        *reinterpret_cast<uint4*>(&As[srow][scol])     = *reinterpret_cast<const uint4*>(ga);
        *reinterpret_cast<uint4*>(&As[srow][scol + 8]) = *reinterpret_cast<const uint4*>(ga + 8);
        *reinterpret_cast<uint4*>(&Bs[srow][scol])     = *reinterpret_cast<const uint4*>(gb);
        *reinterpret_cast<uint4*>(&Bs[srow][scol + 8]) = *reinterpret_cast<const uint4*>(gb + 8);
        __syncthreads();
        bhalf8 af[4], bf[4];
#pragma unroll
        for (int mt = 0; mt < 4; ++mt)
            af[mt] = *reinterpret_cast<const bhalf8*>(&As[m0w + mt * 16 + l15][quad * 8]);
#pragma unroll
        for (int nt = 0; nt < 4; ++nt)
            bf[nt] = *reinterpret_cast<const bhalf8*>(&Bs[n0w + nt * 16 + l15][quad * 8]);
#pragma unroll
        for (int mt = 0; mt < 4; ++mt)
#pragma unroll
            for (int nt = 0; nt < 4; ++nt)
                acc[mt][nt] = __builtin_amdgcn_mfma_f32_16x16x32_bf16(
                    af[mt], bf[nt], acc[mt][nt], 0, 0, 0);
        __syncthreads();
    }
#pragma unroll
    for (int mt = 0; mt < 4; ++mt)
#pragma unroll
        for (int nt = 0; nt < 4; ++nt) {
            int col = col0 + n0w + nt * 16 + l15;
#pragma unroll
            for (int r = 0; r < 4; ++r) {
                int row = row0 + m0w + mt * 16 + quad * 4 + r;
                long off = (long)row * ldc + col;
                float v = acc[mt][nt][r];
                C[off] = acc_flag ? (C[off] + v) : v;
            }
        }
}

// ---------------------------------------------------------------------------
// flat fp32 -> bf16 convert (n mult of 4)
// ---------------------------------------------------------------------------
__global__ __launch_bounds__(256) void cvt_bf16(
    const float* __restrict__ in, u16* __restrict__ out, long n)
{
    long i = ((long)blockIdx.x * 256 + threadIdx.x) * 4;
    if (i >= n) return;
    float4 v = *reinterpret_cast<const float4*>(&in[i]);
    ushort4 o;
    o.x = f2bf(v.x); o.y = f2bf(v.y); o.z = f2bf(v.z); o.w = f2bf(v.w);
    *reinterpret_cast<ushort4*>(&out[i]) = o;
}

// ---------------------------------------------------------------------------
// batched transpose + cvt: in[z] (R,C) ld=ldin  ->  out[z] (C,R) bf16 ld=ldout
// grid (C/64, R/64, 8)
// ---------------------------------------------------------------------------
template <typename TIN>
__global__ __launch_bounds__(256) void transpose_cvt(
    const TIN* __restrict__ in, int ldin, long inOo, long inOi,
    u16* __restrict__ out, int ldout, long outOo, long outOi)
{
    int z = blockIdx.z;
    in  += (long)(z >> 2) * inOo + (long)(z & 3) * inOi;
    out += (long)(z >> 2) * outOo + (long)(z & 3) * outOi;
    int r0 = blockIdx.y * 64, c0 = blockIdx.x * 64;
    __shared__ float t[64][65];
    for (int i = threadIdx.x; i < 4096; i += 256) {
        int r = i >> 6, c = i & 63;
        t[r][c] = ldval(&in[(long)(r0 + r) * ldin + c0 + c]);
    }
    __syncthreads();
    for (int i = threadIdx.x; i < 4096; i += 256) {
        int r = i >> 6, c = i & 63;
        out[(long)(c0 + r) * ldout + r0 + c] = f2bf(t[c][r]);
    }
}

// ---------------------------------------------------------------------------
// lr = softplus(hs @ lr_w^T + lr_b + BASE_LR_INV)  -> (4096, 12)
// ---------------------------------------------------------------------------
__global__ __launch_bounds__(256) void lr_kernel(
    const float* __restrict__ hs, const float* __restrict__ lr_w,
    const float* __restrict__ lr_b, float* __restrict__ lr)
{
    int row = blockIdx.x;
    __shared__ float hrow[2048];
    __shared__ float red[256];
    for (int i = threadIdx.x; i < 2048; i += 256) hrow[i] = hs[(long)row * 2048 + i];
    __syncthreads();
    for (int j = 0; j < 12; ++j) {
        float ss = 0.f;
        for (int i = threadIdx.x; i < 2048; i += 256) ss += hrow[i] * lr_w[(long)j * 2048 + i];
        red[threadIdx.x] = ss; __syncthreads();
        for (int s_ = 128; s_ > 0; s_ >>= 1) {
            if (threadIdx.x < s_) red[threadIdx.x] += red[threadIdx.x + s_];
            __syncthreads();
        }
        if (threadIdx.x == 0) {
            float x = red[0] + lr_b[j] + BASE_LR_INV;
            lr[(long)row * 12 + j] = (x > 20.f) ? x : log1pf(expf(x));
        }
        __syncthreads();
    }
}

// ---------------------------------------------------------------------------
// rmsnorm over d=2048 + RoPE per head (hd=128) -> packed (b,s,16,128)
// ---------------------------------------------------------------------------
__global__ __launch_bounds__(256) void rmsnorm_rope(
    const float* __restrict__ qkv, int colOff, const float* __restrict__ w,
    float* __restrict__ out)
{
    int row = blockIdx.x;            // b*s
    int si = row & (S - 1);
    const float* x = &qkv[(long)row * 6144 + colOff];
    __shared__ float xn[2048];
    __shared__ float red[256];
    float ss = 0.f;
    for (int i = threadIdx.x; i < 2048; i += 256) { float v = x[i]; ss += v * v; }
    red[threadIdx.x] = ss; __syncthreads();
    for (int s_ = 128; s_ > 0; s_ >>= 1) {
        if (threadIdx.x < s_) red[threadIdx.x] += red[threadIdx.x + s_];
        __syncthreads();
    }
    float scale = rsqrtf(red[0] / 2048.f + 1e-6f);
    for (int i = threadIdx.x; i < 2048; i += 256) xn[i] = x[i] * scale * w[i];
    __syncthreads();
    for (int i = threadIdx.x; i < 2048; i += 256) {
        int tt = i & 127;
        int t2 = tt & 63;
        float inv_freq = powf(500000.0f, -(float)t2 / 64.0f);
        float ang = (float)si * inv_freq;
        float sn, cs;
        sincosf(ang, &sn, &cs);
        float v;
        if (tt < 64) v = xn[i] * cs - xn[i + 64] * sn;
        else         v = xn[i] * cs + xn[i - 64] * sn;
        out[(long)row * 2048 + i] = v;
    }
}

// ---------------------------------------------------------------------------
// Flash-style sliding-window causal attention (fp32 VALU).
// ---------------------------------------------------------------------------
__global__ __launch_bounds__(256) void attn_tiled(
    const float* __restrict__ aq, const float* __restrict__ ak,
    const float* __restrict__ qkv, float* __restrict__ attn_out)
{
    const int qt = blockIdx.x;
    const int h  = blockIdx.y;
    const int b_ = blockIdx.z;
    const int q0 = qt * 64;
    const int tid = threadIdx.x;
    const int tx = tid & 15, ty = tid >> 4;
    const float scale = 0.088388347648318447f;

    __shared__ float As[16][68];
    __shared__ float Bs[16][68];
    __shared__ float Ps[64][65];
    __shared__ float Vs[16][132];
    __shared__ float rowred[64][17];
    __shared__ float tmax[64], tsum[64];

    float O[4][8] = {};
    float m_i[4] = {-3.4e38f, -3.4e38f, -3.4e38f, -3.4e38f};
    float l_i[4] = {};

    const long qbase = (long)(b_ * S + q0) * 2048 + h * 128;

    const int st = (qt >= 16) ? (qt - 16) : 0;
    for (int kt = st; kt <= qt; ++kt) {
        const int j0 = kt * 64;
        const long kbase = (long)(b_ * S + j0) * 2048 + h * 128;

        float acc[4][4] = {};
        for (int cc = 0; cc < 128; cc += 16) {
            for (int i = tid; i < 1024; i += 256) {
                int r = i >> 4, c = i & 15;
                As[c][r] = aq[qbase + (long)r * 2048 + cc + c];
                Bs[c][r] = ak[kbase + (long)r * 2048 + cc + c];
            }
            __syncthreads();
#pragma unroll
            for (int k = 0; k < 16; ++k) {
                float4 ra = *reinterpret_cast<const float4*>(&As[k][ty << 2]);
                float4 rb = *reinterpret_cast<const float4*>(&Bs[k][tx << 2]);
                float fa[4] = {ra.x, ra.y, ra.z, ra.w};
                float fb[4] = {rb.x, rb.y, rb.z, rb.w};
#pragma unroll
                for (int a = 0; a < 4; ++a)
#pragma unroll
                    for (int b = 0; b < 4; ++b) acc[a][b] += fa[a] * fb[b];
            }
            __syncthreads();
        }

        float s[4][4];
#pragma unroll
        for (int a = 0; a < 4; ++a) {
            int i_abs = q0 + ty * 4 + a;
            float rm = -3.4e38f;
#pragma unroll
            for (int b = 0; b < 4; ++b) {
                int j_abs = j0 + tx * 4 + b;
                bool valid = (j_abs <= i_abs) && (i_abs - j_abs < 1024);
                s[a][b] = valid ? acc[a][b] * scale : -3.4e38f;
                rm = fmaxf(rm, s[a][b]);
            }
            rowred[ty * 4 + a][tx] = rm;
        }
        __syncthreads();
        if (tid < 64) {
            float rm = -3.4e38f;
#pragma unroll
            for (int j = 0; j < 16; ++j) rm = fmaxf(rm, rowred[tid][j]);
            tmax[tid] = rm;
        }
        __syncthreads();

        float alpha[4];
#pragma unroll
        for (int a = 0; a < 4; ++a) {
            int r = ty * 4 + a;
            float m_new = fmaxf(m_i[a], tmax[r]);
            alpha[a] = expf(m_i[a] - m_new);
            m_i[a] = m_new;
            float psum = 0.f;
#pragma unroll
            for (int b = 0; b < 4; ++b) {
                float p = (s[a][b] > -1e30f) ? expf(s[a][b] - m_new) : 0.f;
                Ps[r][tx * 4 + b] = p;
                psum += p;
            }
            rowred[r][tx] = psum;
#pragma unroll
            for (int c = 0; c < 8; ++c) O[a][c] *= alpha[a];
        }
        __syncthreads();
        if (tid < 64) {
            float rs = 0.f;
#pragma unroll
            for (int j = 0; j < 16; ++j) rs += rowred[tid][j];
            tsum[tid] = rs;
        }
        __syncthreads();
#pragma unroll
        for (int a = 0; a < 4; ++a)
            l_i[a] = l_i[a] * alpha[a] + tsum[ty * 4 + a];

        const long vbase = (long)(b_ * S + j0) * 6144 + 4096 + h * 128;
        for (int kc = 0; kc < 4; ++kc) {
            __syncthreads();
            for (int i = tid; i < 512; i += 256) {
                int kr = i >> 5, c4 = i & 31;
                *reinterpret_cast<float4*>(&Vs[kr][c4 * 4]) =
                    *reinterpret_cast<const float4*>(&qkv[vbase + (long)(kc * 16 + kr) * 6144 + c4 * 4]);
            }
            __syncthreads();
#pragma unroll
            for (int kk = 0; kk < 16; ++kk) {
                float fa[4];
#pragma unroll
                for (int a = 0; a < 4; ++a) fa[a] = Ps[ty * 4 + a][kc * 16 + kk];
                float4 v0 = *reinterpret_cast<const float4*>(&Vs[kk][tx * 8]);
                float4 v1 = *reinterpret_cast<const float4*>(&Vs[kk][tx * 8 + 4]);
                float fb[8] = {v0.x, v0.y, v0.z, v0.w, v1.x, v1.y, v1.z, v1.w};
#pragma unroll
                for (int a = 0; a < 4; ++a)
#pragma unroll
                    for (int c = 0; c < 8; ++c) O[a][c] += fa[a] * fb[c];
            }
        }
        __syncthreads();
    }

#pragma unroll
    for (int a = 0; a < 4; ++a) {
        float inv = 1.0f / l_i[a];
        float4 o0 = make_float4(O[a][0] * inv, O[a][1] * inv, O[a][2] * inv, O[a][3] * inv);
        float4 o1 = make_float4(O[a][4] * inv, O[a][5] * inv, O[a][6] * inv, O[a][7] * inv);
        float* dst = &attn_out[qbase + (long)(ty * 4 + a) * 2048 + tx * 8];
        *reinterpret_cast<float4*>(dst) = o0;
        *reinterpret_cast<float4*>(dst + 4) = o1;
    }
}

// ---------------------------------------------------------------------------
// fq/fk/fv: silu (+affine for q/k) (+L2 norm over fd=512 for q/k) -> bf16
// ---------------------------------------------------------------------------
__global__ __launch_bounds__(128) void fqkv_kernel(
    const float* __restrict__ qkv, const float* __restrict__ qk_scale,
    const float* __restrict__ qk_offset, u16* __restrict__ out, int mode)
{
    int bid = blockIdx.x;
    int nh = bid & 3;
    int row = bid >> 2;
    const float* x = &qkv[(long)row * 6144 + mode * 2048 + nh * 512];
    __shared__ float red[128];
    float vals[4];
    float ss = 0.f;
#pragma unroll
    for (int ii = 0; ii < 4; ++ii) {
        int i = threadIdx.x + ii * 128;
        float v = x[i];
        float sg = 1.f / (1.f + expf(-v));
        float sv = v * sg;
        if (mode < 2) {
            int dcol = nh * 512 + i;
            sv = sv * qk_scale[dcol * 2 + mode] + qk_offset[dcol * 2 + mode];
        }
        vals[ii] = sv;
        ss += sv * sv;
    }
    float invn = 1.0f;
    if (mode < 2) {
        red[threadIdx.x] = ss; __syncthreads();
        for (int s_ = 64; s_ > 0; s_ >>= 1) {
            if (threadIdx.x < s_) red[threadIdx.x] += red[threadIdx.x + s_];
            __syncthreads();
        }
        invn = 1.0f / (sqrtf(red[0]) + 1e-12f);
    }
    u16* o = &out[(long)row * 2048 + nh * 512];
#pragma unroll
    for (int ii = 0; ii < 4; ++ii) o[threadIdx.x + ii * 128] = f2bf(vals[ii] * invn);
}

// ---------------------------------------------------------------------------
// fast-weight init: tile (4,512,512) x b=2 -> (8,512,512) fp32
// ---------------------------------------------------------------------------
__global__ void winit(const float* __restrict__ w0, const float* __restrict__ w1,
                      const float* __restrict__ w2, float* __restrict__ w0b,
                      float* __restrict__ w1b, float* __restrict__ w2b)
{
    long idx = (long)blockIdx.x * 256 + threadIdx.x;
    long src = ((idx >> 18) & 3) * 262144 + (idx & 262143);
    w0b[idx] = w0[src];
    w1b[idx] = w1[src];
    w2b[idx] = w2[src];
}

// ---------------------------------------------------------------------------
// scan elementwise 1 (fp32 temps in place; fv read as bf16)
// ---------------------------------------------------------------------------
__global__ void scan_ew1(const float* gate, const float* hpre, const float* dhb,
                         const u16* fvb, const float* lr, int c0,
                         float* T1, float* T2, float* T3, float* T4)
{
    long idx = (long)blockIdx.x * 256 + threadIdx.x;  // 8*1024*512
    int f = (int)(idx & 511);
    long r = idx >> 9;
    int ci = (int)(r & 1023);
    int z = (int)(r >> 10);
    int b_ = z >> 2, h = z & 3;
    long srow = (long)b_ * S + (long)c0 * CHUNK + ci;
    float g = gate[idx], hp = hpre[idx], dh = dhb[idx];
    float sg = 1.f / (1.f + expf(-g));
    float silu_g = g * sg;
    float hid = silu_g * hp;
    float dgate = dh * hp * (sg * (1.f + g * (1.f - sg)));
    float dhpre = dh * silu_g;
    float l0 = lr[srow * 12 + h];
    float l1 = lr[srow * 12 + 4 + h];
    float l2 = lr[srow * 12 + 8 + h];
    float fvv = bf2f(fvb[srow * 2048 + h * 512 + f]);
    T1[idx] = dgate * l0;
    T2[idx] = dhpre * l2;
    T3[idx] = fvv * l1;
    T4[idx] = hid;
}

// scan elementwise 2: T1 = silu(T1) * T2
__global__ void scan_ew2(float* T1, const float* T2)
{
    long idx = (long)blockIdx.x * 256 + threadIdx.x;
    float g = T1[idx];
    T1[idx] = g * (1.f / (1.f + expf(-g))) * T2[idx];
}

// ---------------------------------------------------------------------------
// ttt rmsnorm added into attn_out in place
// ---------------------------------------------------------------------------
__global__ __launch_bounds__(128) void ttt_norm_add(
    const float* __restrict__ ttt, const float* __restrict__ w, float* attnX)
{
    int bid = blockIdx.x;
    int h = bid & 3;
    int row = bid >> 2;
    const float* x = &ttt[(long)row * 2048 + h * 512];
    __shared__ float red[128];
    float v[4];
    float ss = 0.f;
#pragma unroll
    for (int ii = 0; ii < 4; ++ii) {
        v[ii] = x[threadIdx.x + ii * 128];
        ss += v[ii] * v[ii];
    }
    red[threadIdx.x] = ss; __syncthreads();
    for (int s_ = 64; s_ > 0; s_ >>= 1) {
        if (threadIdx.x < s_) red[threadIdx.x] += red[threadIdx.x + s_];
        __syncthreads();
    }
    float sc = rsqrtf(red[0] / 512.f + 1e-6f);
    float* o = &attnX[(long)row * 2048 + h * 512];
#pragma unroll
    for (int ii = 0; ii < 4; ++ii) {
        int i = threadIdx.x + ii * 128;
        o[i] = o[i] + v[ii] * sc * w[i];
    }
}

// ---------------------------------------------------------------------------
extern "C" void kernel_launch(void* const* d_in, const int* in_sizes, int n_in,
                              void* d_out, int out_size, void* d_ws, size_t ws_size,
                              hipStream_t stream)
{
    const float* hs        = (const float*)d_in[0];
    const float* Wqkv      = (const float*)d_in[1];
    const float* Wo        = (const float*)d_in[2];
    const float* q_norm_w  = (const float*)d_in[3];
    const float* k_norm_w  = (const float*)d_in[4];
    const float* w0        = (const float*)d_in[5];
    const float* w1        = (const float*)d_in[6];
    const float* w2        = (const float*)d_in[7];
    const float* lr_w      = (const float*)d_in[8];
    const float* lr_b      = (const float*)d_in[9];
    const float* qk_scale  = (const float*)d_in[10];
    const float* qk_offset = (const float*)d_in[11];
    const float* ttt_w     = (const float*)d_in[12];
    float* out = (float*)d_out;
    float* ws = (float*)d_ws;

    // ---- workspace (fp32 units), total 65,060,864 floats = 248.2 MiB -------
    const long F_QKV = 0;          // qkv fp32 (25,165,824); later:
    const long F_TTT = 0;          //   ttt fp32 (8,388,608)
    const long F_T1  = 8388608;    //   T1..T4 fp32 (4 x 4,194,304)
    const long F_T2  = 12582912;
    const long F_T3  = 16777216;
    const long F_T4  = 20971520;
    const long F_AQ  = 25165824;   // hs_b -> aq fp32 -> fq_b | fk_b
    const long F_AK  = 33554432;   // Wqkv_b -> ak fp32 -> fv_b | hq_b | fkt
    const long F_ATT = 41943040;   // attX fp32 (8,388,608)
    const long F_TTa = 50331648;   // transposed bf16 temp A (2,097,152)
    const long F_TTb = 52428800;   // transposed bf16 temp B (2,097,152)
    const long F_W0  = 54525952;   // weights fp32 (3 x 2,097,152)
    const long F_W1  = 56623104;
    const long F_W2  = 58720256;
    const long F_W0B = 60817408;   // bf16 snapshots (4 x 1,048,576)
    const long F_W1B = 61865984;
    const long F_W2B = 62914560;
    const long F_W1T = 63963136;
    const long F_LR  = 65011712;   // end 65,060,864

    u16* hs_b   = (u16*)(ws + F_AQ);
    u16* wqkv_b = (u16*)(ws + F_AK);
    u16* fq_b   = (u16*)(ws + F_AQ);
    u16* fk_b   = (u16*)(ws + F_AQ + 4194304);
    u16* fv_b   = (u16*)(ws + F_AK);
    u16* hq_b   = (u16*)(ws + F_AK + 4194304);
    u16* fkt_b  = (u16*)(ws + F_AK + 6291456);
    u16* tta    = (u16*)(ws + F_TTa);
    u16* ttb    = (u16*)(ws + F_TTb);
    u16* w0b_u  = (u16*)(ws + F_W0B);
    u16* w1b_u  = (u16*)(ws + F_W1B);
    u16* w2b_u  = (u16*)(ws + F_W2B);
    u16* w1t_u  = (u16*)(ws + F_W1T);
    u16* x_b    = (u16*)(ws + F_T1);   // after scan
    u16* wo_b   = (u16*)(ws + F_T3);   // after scan

    // 1. qkv = hs @ Wqkv^T  (bf16 MFMA)
    cvt_bf16<<<8192, 256, 0, stream>>>(hs, hs_b, 8388608);
    cvt_bf16<<<12288, 256, 0, stream>>>(Wqkv, wqkv_b, 12582912);
    gemm_mfma<<<dim3(48, 32, 1), 256, 0, stream>>>(
        hs_b, 2048, 0, 0, wqkv_b, 2048, 0, 0, ws + F_QKV, 6144, 0, 0, 2048, 0);
    // 2. lr
    lr_kernel<<<4096, 256, 0, stream>>>(hs, lr_w, lr_b, ws + F_LR);
    // 3. rmsnorm + rope (overwrites hs_b / wqkv_b — they are dead)
    rmsnorm_rope<<<4096, 256, 0, stream>>>(ws + F_QKV, 0,    q_norm_w, ws + F_AQ);
    rmsnorm_rope<<<4096, 256, 0, stream>>>(ws + F_QKV, 2048, k_norm_w, ws + F_AK);
    // 4. attention
    attn_tiled<<<dim3(32, 16, 2), 256, 0, stream>>>(
        ws + F_AQ, ws + F_AK, ws + F_QKV, ws + F_ATT);
    // 5. fq/fk/fv bf16 (overwrite aq/ak regions — dead after attention)
    fqkv_kernel<<<16384, 128, 0, stream>>>(ws + F_QKV, qk_scale, qk_offset, fq_b, 0);
    fqkv_kernel<<<16384, 128, 0, stream>>>(ws + F_QKV, qk_scale, qk_offset, fk_b, 1);
    fqkv_kernel<<<16384, 128, 0, stream>>>(ws + F_QKV, qk_scale, qk_offset, fv_b, 2);
    // 6. fast-weight init (fp32 masters)
    winit<<<8192, 256, 0, stream>>>(w0, w1, w2, ws + F_W0, ws + F_W1, ws + F_W2);

    for (int c0 = 0; c0 < 2; ++c0) {
        const long cOff = (long)c0 * 2097152;           // chunk offset in bf16 elems
        // bf16 snapshots of weights + w1^T
        cvt_bf16<<<2048, 256, 0, stream>>>(ws + F_W0, w0b_u, 2097152);
        cvt_bf16<<<2048, 256, 0, stream>>>(ws + F_W2, w2b_u, 2097152);
        transpose_cvt<float><<<dim3(8, 8, 8), 256, 0, stream>>>(
            ws + F_W1, 512, 1048576, 262144, w1t_u, 512, 1048576, 262144);
        // fk^T for the updates
        transpose_cvt<u16><<<dim3(8, 16, 8), 256, 0, stream>>>(
            fk_b + cOff, 2048, 4194304, 512, fkt_b, 1024, 2097152, 524288);
        // gate / hpre / dh
        gemm_mfma<<<dim3(4, 8, 8), 256, 0, stream>>>(
            fk_b + cOff, 2048, 4194304, 512, w0b_u, 512, 1048576, 262144,
            ws + F_T1, 512, 2097152, 524288, 512, 0);
        gemm_mfma<<<dim3(4, 8, 8), 256, 0, stream>>>(
            fk_b + cOff, 2048, 4194304, 512, w2b_u, 512, 1048576, 262144,
            ws + F_T2, 512, 2097152, 524288, 512, 0);
        gemm_mfma<<<dim3(4, 8, 8), 256, 0, stream>>>(
            fv_b + cOff, 2048, 4194304, 512, w1t_u, 512, 1048576, 262144,
            ws + F_T3, 512, 2097152, 524288, 512, 0);
        // elementwise
        scan_ew1<<<16384, 256, 0, stream>>>(ws + F_T1, ws + F_T2, ws + F_T3,
                                            fv_b, ws + F_LR, c0,
                                            ws + F_T1, ws + F_T2, ws + F_T3, ws + F_T4);
        // w0 / w2 updates: transpose T1,T2 then C += A^T-form MFMA
        transpose_cvt<float><<<dim3(8, 16, 8), 256, 0, stream>>>(
            ws + F_T1, 512, 2097152, 524288, tta, 1024, 2097152, 524288);
        transpose_cvt<float><<<dim3(8, 16, 8), 256, 0, stream>>>(
            ws + F_T2, 512, 2097152, 524288, ttb, 1024, 2097152, 524288);
        gemm_mfma<<<dim3(4, 4, 8), 256, 0, stream>>>(
            tta, 1024, 2097152, 524288, fkt_b, 1024, 2097152, 524288,
            ws + F_W0, 512, 1048576, 262144, 1024, 1);
        gemm_mfma<<<dim3(4, 4, 8), 256, 0, stream>>>(
            ttb, 1024, 2097152, 524288, fkt_b, 1024, 2097152, 524288,
            ws + F_W2, 512, 1048576, 262144, 1024, 1);
        // w1 update: transpose T3,T4
        transpose_cvt<float><<<dim3(8, 16, 8), 256, 0, stream>>>(
            ws + F_T3, 512, 2097152, 524288, tta, 1024, 2097152, 524288);
        transpose_cvt<float><<<dim3(8, 16, 8), 256, 0, stream>>>(
            ws + F_T4, 512, 2097152, 524288, ttb, 1024, 2097152, 524288);
        gemm_mfma<<<dim3(4, 4, 8), 256, 0, stream>>>(
            tta, 1024, 2097152, 524288, ttb, 1024, 2097152, 524288,
            ws + F_W1, 512, 1048576, 262144, 1024, 1);
        // query pass with updated weights
        cvt_bf16<<<2048, 256, 0, stream>>>(ws + F_W0, w0b_u, 2097152);
        cvt_bf16<<<2048, 256, 0, stream>>>(ws + F_W2, w2b_u, 2097152);
        cvt_bf16<<<2048, 256, 0, stream>>>(ws + F_W1, w1b_u, 2097152);
        gemm_mfma<<<dim3(4, 8, 8), 256, 0, stream>>>(
            fq_b + cOff, 2048, 4194304, 512, w0b_u, 512, 1048576, 262144,
            ws + F_T1, 512, 2097152, 524288, 512, 0);
        gemm_mfma<<<dim3(4, 8, 8), 256, 0, stream>>>(
            fq_b + cOff, 2048, 4194304, 512, w2b_u, 512, 1048576, 262144,
            ws + F_T2, 512, 2097152, 524288, 512, 0);
        scan_ew2<<<16384, 256, 0, stream>>>(ws + F_T1, ws + F_T2);
        cvt_bf16<<<4096, 256, 0, stream>>>(ws + F_T1, hq_b, 4194304);
        // oi = hq @ w1^T -> ttt (strided (b,s,NH,fd))
        gemm_mfma<<<dim3(4, 8, 8), 256, 0, stream>>>(
            hq_b, 512, 2097152, 524288, w1b_u, 512, 1048576, 262144,
            ws + F_TTT + cOff, 2048, 4194304, 512, 512, 0);
    }

    // 8. ttt rmsnorm + add into attX
    ttt_norm_add<<<16384, 128, 0, stream>>>(ws + F_TTT, ttt_w, ws + F_ATT);
    // 9. out = X @ Wo^T  (bf16 MFMA; X_b/Wo_b reuse dead T region)
    cvt_bf16<<<8192, 256, 0, stream>>>(ws + F_ATT, x_b, 8388608);
    cvt_bf16<<<4096, 256, 0, stream>>>(Wo, wo_b, 4194304);
    gemm_mfma<<<dim3(16, 32, 1), 256, 0, stream>>>(
        x_b, 2048, 0, 0, wo_b, 2048, 0, 0, out, 2048, 0, 0, 2048, 0);
}